// Round 4
// baseline (503.535 us; speedup 1.0000x reference)
//
#include <hip/hip_runtime.h>

// x        [64, 524288] f32 | idx_feat [4096,256] f32 | weight [64,256] f32
// bias     [64] f32         | pred_cate [4096] i32    | pred_score [4096] f32
// out (f32 concat): seg_pred [53*524288], unique_cate [53], fused_score [53]

#define KK   4096
#define CIN  256
#define CC   64
#define HW   524288   // 512*1024
#define HW4  (HW / 4) // float4 columns
#define UU   53
#define FWS  56       // fwt row stride (53 padded)

// ws layout (floats) — only fwt; no atomics, no memset needed
#define WS_FWT 0      // fw TRANSPOSED [64][FWS]

typedef float f4 __attribute__((ext_vector_type(4)));

// ---------------------------------------------------------------------------
// Fused stages 1+2 (UNCHANGED): one block per class u (53 blocks, 256 thr).
// ---------------------------------------------------------------------------
__global__ __launch_bounds__(256)
void fused12_kernel(const float* __restrict__ idx_feat,
                    const int*   __restrict__ pred_cate,
                    const float* __restrict__ pred_score,
                    const float* __restrict__ weight,
                    const float* __restrict__ bias,
                    float* __restrict__ ws,
                    float* __restrict__ out)
{
    const int u   = blockIdx.x;
    const int tid = threadIdx.x;

    __shared__ int   list[128];    // max count per class is 78 (4096 = 53*77+15)
    __shared__ int   nmatch;
    __shared__ float sumf[CIN];    // per-cin class feature sums
    __shared__ float wsum[4];      // per-wave score partials

    if (tid == 0) nmatch = 0;
    __syncthreads();

    // ---- Phase A: scan + compact + score ----
    float sc = 0.0f;
    #pragma unroll
    for (int k = tid; k < KK; k += 256) {       // coalesced int loads
        if (pred_cate[k] == u) {
            int pos = atomicAdd(&nmatch, 1);    // LDS atomic, ~77/block total
            list[pos] = k;
            sc += pred_score[k];
        }
    }
    // wave-reduce score (64 lanes)
    #pragma unroll
    for (int off = 32; off > 0; off >>= 1) sc += __shfl_down(sc, off);
    if ((tid & 63) == 0) wsum[tid >> 6] = sc;
    __syncthreads();                            // list + wsum complete

    // ---- Phase B: feature sums, thread owns cin = tid ----
    const int n = nmatch;                       // uniform
    float acc = 0.0f;
    #pragma unroll 4
    for (int m = 0; m < n; ++m) {
        const int k = list[m];                  // uniform LDS broadcast
        acc += idx_feat[(size_t)k * CIN + tid]; // coalesced row load
    }
    sumf[tid] = acc;
    __syncthreads();

    // ---- Phase C: fw[:,u] = (weight @ mean_u) + bias, transposed store ----
    const float inv = 1.0f / (float)n;
    const int c = tid >> 2;                     // output channel 0..63
    const int q = tid & 3;                      // quarter of the 256-dot
    float d = 0.0f;
    const int i0 = q * 64;
    #pragma unroll 8
    for (int i = 0; i < 64; ++i)
        d = fmaf(sumf[i0 + i], weight[(size_t)c * CIN + i0 + i], d);
    d += __shfl_xor(d, 1);
    d += __shfl_xor(d, 2);                      // q-group of 4 summed
    if (q == 0)
        ws[WS_FWT + c * FWS + u] = d * inv + bias[c];

    if (tid == 0) {
        out[(size_t)UU * HW + u]      = (float)u;                       // unique_cate
        out[(size_t)UU * HW + UU + u] = (wsum[0] + wsum[1] + wsum[2] + wsum[3]) * inv; // fused_score
    }
}

// ---------------------------------------------------------------------------
// Stage 3: seg_pred = fw [53,64] @ x [64, HW].
// REVERT to float4/thread (f2 experiment: 89 us, latency-bound at 25% HBM);
// CHANGE: c-loop unroll 2 -> 4. 4 independent nt dwordx4 loads in flight
// per thread = 32 KB/CU at 8 waves/CU, vs ~13.5 KB needed to cover ~900 cyc
// HBM read latency at 3.6 TB/s read share. VGPR ~228 (212 acc + 4 xv),
// fits launch_bounds(256,2). Per-column FMA order identical -> bit-identical.
// Floors: mem 245 MB @ ~6.7 TB/s = 37 us; VALU 22.6 us. f4@unroll2 was ~68 us.
// ---------------------------------------------------------------------------
__global__ __launch_bounds__(256, 2)
void seg_pred_kernel(const float* __restrict__ x,
                     const float* __restrict__ ws,
                     float* __restrict__ out)
{
    const int j = blockIdx.x * 256 + threadIdx.x;   // float4 column index
    const f4* x4   = (const f4*)x;
    f4*       out4 = (f4*)out;
    const float* fwt = ws + WS_FWT;

    f4 acc[UU];
    #pragma unroll
    for (int u = 0; u < UU; ++u) acc[u] = (f4)0.0f;

    #pragma unroll 4
    for (int c = 0; c < CC; ++c) {
        const f4 xv = __builtin_nontemporal_load(&x4[(size_t)c * HW4 + j]);
        #pragma unroll
        for (int u = 0; u < UU; ++u) {
            const float w = fwt[c * FWS + u];        // uniform, consecutive
            acc[u].x = fmaf(w, xv.x, acc[u].x);
            acc[u].y = fmaf(w, xv.y, acc[u].y);
            acc[u].z = fmaf(w, xv.z, acc[u].z);
            acc[u].w = fmaf(w, xv.w, acc[u].w);
        }
    }

    #pragma unroll
    for (int u = 0; u < UU; ++u)
        __builtin_nontemporal_store(acc[u], &out4[(size_t)u * HW4 + j]);
}

extern "C" void kernel_launch(void* const* d_in, const int* in_sizes, int n_in,
                              void* d_out, int out_size, void* d_ws, size_t ws_size,
                              hipStream_t stream)
{
    const float* x          = (const float*)d_in[0];
    const float* idx_feat   = (const float*)d_in[1];
    const float* weight     = (const float*)d_in[2];
    const float* bias       = (const float*)d_in[3];
    const int*   pred_cate  = (const int*)d_in[4];
    const float* pred_score = (const float*)d_in[5];

    float* out = (float*)d_out;
    float* ws  = (float*)d_ws;

    fused12_kernel<<<UU, 256, 0, stream>>>(idx_feat, pred_cate, pred_score,
                                           weight, bias, ws, out);
    seg_pred_kernel<<<HW4 / 256, 256, 0, stream>>>(x, ws, out);  // 512 blocks
}

// Round 5
// 294.425 us; speedup vs baseline: 1.7102x; 1.7102x over previous
//
#include <hip/hip_runtime.h>

// x        [64, 524288] f32 | idx_feat [4096,256] f32 | weight [64,256] f32
// bias     [64] f32         | pred_cate [4096] i32    | pred_score [4096] f32
// out (f32 concat): seg_pred [53*524288], unique_cate [53], fused_score [53]

#define KK   4096
#define CIN  256
#define CC   64
#define HW   524288   // 512*1024
#define HW4  (HW / 4) // float4 columns
#define UU   53
#define FWS  56       // fwt row stride (53 padded; reads up to index 55 ok)
#define UH   27       // classes per u-half (half 0: 27, half 1: 26)

// ws layout (floats) — only fwt; no atomics, no memset needed
#define WS_FWT 0      // fw TRANSPOSED [64][FWS]

typedef float f4 __attribute__((ext_vector_type(4)));

// ---------------------------------------------------------------------------
// Fused stages 1+2 (UNCHANGED): one block per class u (53 blocks, 256 thr).
// ---------------------------------------------------------------------------
__global__ __launch_bounds__(256)
void fused12_kernel(const float* __restrict__ idx_feat,
                    const int*   __restrict__ pred_cate,
                    const float* __restrict__ pred_score,
                    const float* __restrict__ weight,
                    const float* __restrict__ bias,
                    float* __restrict__ ws,
                    float* __restrict__ out)
{
    const int u   = blockIdx.x;
    const int tid = threadIdx.x;

    __shared__ int   list[128];    // max count per class is 78 (4096 = 53*77+15)
    __shared__ int   nmatch;
    __shared__ float sumf[CIN];    // per-cin class feature sums
    __shared__ float wsum[4];      // per-wave score partials

    if (tid == 0) nmatch = 0;
    __syncthreads();

    // ---- Phase A: scan + compact + score ----
    float sc = 0.0f;
    #pragma unroll
    for (int k = tid; k < KK; k += 256) {       // coalesced int loads
        if (pred_cate[k] == u) {
            int pos = atomicAdd(&nmatch, 1);    // LDS atomic, ~77/block total
            list[pos] = k;
            sc += pred_score[k];
        }
    }
    // wave-reduce score (64 lanes)
    #pragma unroll
    for (int off = 32; off > 0; off >>= 1) sc += __shfl_down(sc, off);
    if ((tid & 63) == 0) wsum[tid >> 6] = sc;
    __syncthreads();                            // list + wsum complete

    // ---- Phase B: feature sums, thread owns cin = tid ----
    const int n = nmatch;                       // uniform
    float acc = 0.0f;
    #pragma unroll 4
    for (int m = 0; m < n; ++m) {
        const int k = list[m];                  // uniform LDS broadcast
        acc += idx_feat[(size_t)k * CIN + tid]; // coalesced row load
    }
    sumf[tid] = acc;
    __syncthreads();

    // ---- Phase C: fw[:,u] = (weight @ mean_u) + bias, transposed store ----
    const float inv = 1.0f / (float)n;
    const int c = tid >> 2;                     // output channel 0..63
    const int q = tid & 3;                      // quarter of the 256-dot
    float d = 0.0f;
    const int i0 = q * 64;
    #pragma unroll 8
    for (int i = 0; i < 64; ++i)
        d = fmaf(sumf[i0 + i], weight[(size_t)c * CIN + i0 + i], d);
    d += __shfl_xor(d, 1);
    d += __shfl_xor(d, 2);                      // q-group of 4 summed
    if (q == 0)
        ws[WS_FWT + c * FWS + u] = d * inv + bias[c];

    if (tid == 0) {
        out[(size_t)UU * HW + u]      = (float)u;                       // unique_cate
        out[(size_t)UU * HW + UU + u] = (wsum[0] + wsum[1] + wsum[2] + wsum[3]) * inv; // fused_score
    }
}

// ---------------------------------------------------------------------------
// Stage 3: seg_pred = fw [53,64] @ x [64, HW], u-SPLIT 2-way.
// Round-4 lesson: 212 acc VGPR + unroll-4 pipeline -> allocator clamped to
// 128 VGPR and spilled 550 MB to scratch (WRITE 661 MB). Fix is structural:
// block b = (j-block b>>1, u-half b&1); acc = 27 f4 = 108 VGPR, ~150 total
// with 4-deep load pipeline -> no allocator cliff, ~3 waves/SIMD actual.
// x streamed twice, but pair-blocks share j concurrently and x (134 MB)
// fits L3 (round-3 FETCH 65 MB < 134 MB proved L3 serves nt loads) ->
// HBM traffic stays ~245 MB. Per-output FMA order unchanged -> bit-identical.
// Floors: mem 245 MB @ ~6.7 TB/s = 37 us; VALU 22.6 us.
// ---------------------------------------------------------------------------
__global__ __launch_bounds__(256, 2)
void seg_pred_kernel(const float* __restrict__ x,
                     const float* __restrict__ ws,
                     float* __restrict__ out)
{
    const int b    = blockIdx.x;
    const int half = b & 1;
    const int j    = (b >> 1) * 256 + threadIdx.x;  // float4 column index
    const int u0   = half * UH;                     // 0 or 27
    const f4* x4   = (const f4*)x;
    f4*       out4 = (f4*)out;
    const float* fwt = ws + WS_FWT + u0;

    f4 acc[UH];
    #pragma unroll
    for (int u = 0; u < UH; ++u) acc[u] = (f4)0.0f;

    #pragma unroll 4
    for (int c = 0; c < CC; ++c) {
        const f4 xv = __builtin_nontemporal_load(&x4[(size_t)c * HW4 + j]);
        #pragma unroll
        for (int u = 0; u < UH; ++u) {
            const float w = fwt[c * FWS + u];        // uniform, consecutive
            acc[u].x = fmaf(w, xv.x, acc[u].x);      // (u0+26 for half 1 reads
            acc[u].y = fmaf(w, xv.y, acc[u].y);      //  pad col 53<56: unused)
            acc[u].z = fmaf(w, xv.z, acc[u].z);
            acc[u].w = fmaf(w, xv.w, acc[u].w);
        }
    }

    #pragma unroll
    for (int u = 0; u < UH; ++u)
        if (u0 + u < UU)                             // half 1 stores 26 rows
            __builtin_nontemporal_store(acc[u], &out4[(size_t)(u0 + u) * HW4 + j]);
}

extern "C" void kernel_launch(void* const* d_in, const int* in_sizes, int n_in,
                              void* d_out, int out_size, void* d_ws, size_t ws_size,
                              hipStream_t stream)
{
    const float* x          = (const float*)d_in[0];
    const float* idx_feat   = (const float*)d_in[1];
    const float* weight     = (const float*)d_in[2];
    const float* bias       = (const float*)d_in[3];
    const int*   pred_cate  = (const int*)d_in[4];
    const float* pred_score = (const float*)d_in[5];

    float* out = (float*)d_out;
    float* ws  = (float*)d_ws;

    fused12_kernel<<<UU, 256, 0, stream>>>(idx_feat, pred_cate, pred_score,
                                           weight, bias, ws, out);
    seg_pred_kernel<<<2 * (HW4 / 256), 256, 0, stream>>>(x, ws, out);  // 1024 blocks
}

// Round 6
// 268.020 us; speedup vs baseline: 1.8787x; 1.0985x over previous
//
#include <hip/hip_runtime.h>

// x        [64, 524288] f32 | idx_feat [4096,256] f32 | weight [64,256] f32
// bias     [64] f32         | pred_cate [4096] i32    | pred_score [4096] f32
// out (f32 concat): seg_pred [53*524288], unique_cate [53], fused_score [53]

#define KK   4096
#define CIN  256
#define CC   64
#define HW   524288   // 512*1024
#define HW4  (HW / 4) // float4 columns
#define UU   53
#define FWS  56       // fwt row stride (53 padded; half-1 reads pad col 53, never stored)
#define UH   27       // classes per u-half (half 0: 27, half 1: 26)

// ws layout (floats) — only fwt; no atomics, no memset needed
#define WS_FWT 0      // fw TRANSPOSED [64][FWS]

typedef float f4 __attribute__((ext_vector_type(4)));

// ---------------------------------------------------------------------------
// Fused stages 1+2 (UNCHANGED): one block per class u (53 blocks, 256 thr).
// ---------------------------------------------------------------------------
__global__ __launch_bounds__(256)
void fused12_kernel(const float* __restrict__ idx_feat,
                    const int*   __restrict__ pred_cate,
                    const float* __restrict__ pred_score,
                    const float* __restrict__ weight,
                    const float* __restrict__ bias,
                    float* __restrict__ ws,
                    float* __restrict__ out)
{
    const int u   = blockIdx.x;
    const int tid = threadIdx.x;

    __shared__ int   list[128];    // max count per class is 78 (4096 = 53*77+15)
    __shared__ int   nmatch;
    __shared__ float sumf[CIN];    // per-cin class feature sums
    __shared__ float wsum[4];      // per-wave score partials

    if (tid == 0) nmatch = 0;
    __syncthreads();

    // ---- Phase A: scan + compact + score ----
    float sc = 0.0f;
    #pragma unroll
    for (int k = tid; k < KK; k += 256) {       // coalesced int loads
        if (pred_cate[k] == u) {
            int pos = atomicAdd(&nmatch, 1);    // LDS atomic, ~77/block total
            list[pos] = k;
            sc += pred_score[k];
        }
    }
    // wave-reduce score (64 lanes)
    #pragma unroll
    for (int off = 32; off > 0; off >>= 1) sc += __shfl_down(sc, off);
    if ((tid & 63) == 0) wsum[tid >> 6] = sc;
    __syncthreads();                            // list + wsum complete

    // ---- Phase B: feature sums, thread owns cin = tid ----
    const int n = nmatch;                       // uniform
    float acc = 0.0f;
    #pragma unroll 4
    for (int m = 0; m < n; ++m) {
        const int k = list[m];                  // uniform LDS broadcast
        acc += idx_feat[(size_t)k * CIN + tid]; // coalesced row load
    }
    sumf[tid] = acc;
    __syncthreads();

    // ---- Phase C: fw[:,u] = (weight @ mean_u) + bias, transposed store ----
    const float inv = 1.0f / (float)n;
    const int c = tid >> 2;                     // output channel 0..63
    const int q = tid & 3;                      // quarter of the 256-dot
    float d = 0.0f;
    const int i0 = q * 64;
    #pragma unroll 8
    for (int i = 0; i < 64; ++i)
        d = fmaf(sumf[i0 + i], weight[(size_t)c * CIN + i0 + i], d);
    d += __shfl_xor(d, 1);
    d += __shfl_xor(d, 2);                      // q-group of 4 summed
    if (q == 0)
        ws[WS_FWT + c * FWS + u] = d * inv + bias[c];

    if (tid == 0) {
        out[(size_t)UU * HW + u]      = (float)u;                       // unique_cate
        out[(size_t)UU * HW + UU + u] = (wsum[0] + wsum[1] + wsum[2] + wsum[3]) * inv; // fused_score
    }
}

// ---------------------------------------------------------------------------
// Stage 3: seg_pred = fw [53,64] @ x [64, HW], u-SPLIT 2-way.
// Constraint surface learned over rounds 2-5:
//  - VGPR cliff: need <=128 for 4 waves/SIMD (round 5 unroll-4 blew past it,
//    kept 2 waves/SIMD and just paid x-twice: 79 us).
//  - latency: ~13 KB/CU reads in flight needed; 16 waves x 2 KB = 32 KB.
//  - allocator breaks down near 212+ live regs (round 4 spill disaster).
// This version: 27 f4 acc = 108 VGPR, unroll 2 (need ~126), launch_bounds
// (256,4) pins allocator <=128 -> 16 waves/CU. x loads are PLAIN (cached):
// second u-half pass hits L3 (x = 134 MB < 256 MB L3; nt loads in round 5
// did NOT allocate L3 and re-fetched from HBM). Stores stay nontemporal
// (write-only stream). Per-output FMA chain unchanged -> bit-identical.
// Floors: mem 245 MB @ ~6.7 TB/s = 37 us; VALU 22.6 us.
// ---------------------------------------------------------------------------
__global__ __launch_bounds__(256, 4)
void seg_pred_kernel(const float* __restrict__ x,
                     const float* __restrict__ ws,
                     float* __restrict__ out)
{
    const int b    = blockIdx.x;
    const int half = b & 1;
    const int j    = (b >> 1) * 256 + threadIdx.x;  // float4 column index
    const int u0   = half * UH;                     // 0 or 27
    const f4* x4   = (const f4*)x;
    f4*       out4 = (f4*)out;
    const float* fwt = ws + WS_FWT + u0;

    f4 acc[UH];
    #pragma unroll
    for (int u = 0; u < UH; ++u) acc[u] = (f4)0.0f;

    #pragma unroll 2
    for (int c = 0; c < CC; ++c) {
        const f4 xv = x4[(size_t)c * HW4 + j];       // plain load: L2/L3 allocate
        #pragma unroll
        for (int u = 0; u < UH; ++u) {
            const float w = fwt[c * FWS + u];        // uniform, consecutive
            acc[u].x = fmaf(w, xv.x, acc[u].x);      // (half 1, u=26 reads pad
            acc[u].y = fmaf(w, xv.y, acc[u].y);      //  col 53<56: never stored)
            acc[u].z = fmaf(w, xv.z, acc[u].z);
            acc[u].w = fmaf(w, xv.w, acc[u].w);
        }
    }

    #pragma unroll
    for (int u = 0; u < UH; ++u)
        if (u0 + u < UU)                             // half 1 stores 26 rows
            __builtin_nontemporal_store(acc[u], &out4[(size_t)(u0 + u) * HW4 + j]);
}

extern "C" void kernel_launch(void* const* d_in, const int* in_sizes, int n_in,
                              void* d_out, int out_size, void* d_ws, size_t ws_size,
                              hipStream_t stream)
{
    const float* x          = (const float*)d_in[0];
    const float* idx_feat   = (const float*)d_in[1];
    const float* weight     = (const float*)d_in[2];
    const float* bias       = (const float*)d_in[3];
    const int*   pred_cate  = (const int*)d_in[4];
    const float* pred_score = (const float*)d_in[5];

    float* out = (float*)d_out;
    float* ws  = (float*)d_ws;

    fused12_kernel<<<UU, 256, 0, stream>>>(idx_feat, pred_cate, pred_score,
                                           weight, bias, ws, out);
    seg_pred_kernel<<<2 * (HW4 / 256), 256, 0, stream>>>(x, ws, out);  // 1024 blocks
}